// Round 6
// baseline (2359.285 us; speedup 1.0000x reference)
//
#include <hip/hip_runtime.h>

// ---------------------------------------------------------------------------
// LSH self-attention (Reformer). B=2,S=4096,H=16,D=64,NH=2,NB=128,CHUNK=64,
// N_BEFORE=1. Inputs fp32, output fp32.
// Precision-critical path (qk projection + rotated einsum feeding argmax) is
// fp32 with explicit sequential ascending-k FMA chains per output element,
// bit-matching BLAS sgemm microkernel order (np reference arithmetic).
// ---------------------------------------------------------------------------

typedef __attribute__((ext_vector_type(4))) float          f32x4;
typedef __attribute__((ext_vector_type(8))) unsigned short u16x8;

__device__ __forceinline__ float bf2f(unsigned short u) {
    unsigned int x = ((unsigned int)u) << 16;
    return __builtin_bit_cast(float, x);
}
__device__ __forceinline__ unsigned short f2bf(float f) {
    unsigned int x = __builtin_bit_cast(unsigned int, f);
    x += 0x7FFFu + ((x >> 16) & 1u);
    return (unsigned short)(x >> 16);
}

// ---------------------------------------------------------------------------
// Kernel 1a: qk projection. fp32, per-element sequential ascending-k FMA
// (BLAS sgemm order). qk fp32 [B,H,S,D].
// ---------------------------------------------------------------------------
__global__ __launch_bounds__(256)
void gemm_qk(const float* __restrict__ hidden,
             const float* __restrict__ wqk,
             float* __restrict__ qk_out)
{
    __shared__ float As[16][132];
    __shared__ float Bs[16][68];
    const int tid = threadIdx.x;
    const int bm  = blockIdx.x;     // 0..63
    const int bn  = blockIdx.y;     // 0..15

    const float* Asrc = hidden + (size_t)bm * 128 * 1024;
    const float* Bsrc = wqk + (size_t)bn * 64 * 1024;

    const int mt = (tid & 15) * 8;
    const int nt = (tid >> 4) * 4;

    float acc[8][4];
#pragma unroll
    for (int r = 0; r < 8; ++r)
#pragma unroll
        for (int c = 0; c < 4; ++c) acc[r][c] = 0.f;

    int arow[2], akof[2];
#pragma unroll
    for (int i = 0; i < 2; ++i) {
        const int c = i * 256 + tid;
        arow[i] = c >> 2;
        akof[i] = (c & 3) * 4;
    }
    const int brow = tid >> 2;
    const int bkof = (tid & 3) * 4;

    f32x4 apre[2], bpre;
#pragma unroll
    for (int i = 0; i < 2; ++i)
        apre[i] = *(const f32x4*)(Asrc + (size_t)arow[i] * 1024 + akof[i]);
    bpre = *(const f32x4*)(Bsrc + (size_t)brow * 1024 + bkof);

    for (int ks = 0; ks < 64; ++ks) {     // K = 64 tiles * 16, ascending
#pragma unroll
        for (int i = 0; i < 2; ++i)
#pragma unroll
            for (int j = 0; j < 4; ++j)
                As[akof[i] + j][arow[i]] = apre[i][j];
#pragma unroll
        for (int j = 0; j < 4; ++j)
            Bs[bkof + j][brow] = bpre[j];
        __syncthreads();
        if (ks < 63) {
            const int k0 = (ks + 1) * 16;
#pragma unroll
            for (int i = 0; i < 2; ++i)
                apre[i] = *(const f32x4*)(Asrc + (size_t)arow[i] * 1024 + k0 + akof[i]);
            bpre = *(const f32x4*)(Bsrc + (size_t)brow * 1024 + k0 + bkof);
        }
#pragma unroll
        for (int k = 0; k < 16; ++k) {    // ascending within tile
            f32x4 a0 = *(const f32x4*)&As[k][mt];
            f32x4 a1 = *(const f32x4*)&As[k][mt + 4];
            f32x4 b  = *(const f32x4*)&Bs[k][nt];
#pragma unroll
            for (int c = 0; c < 4; ++c) {
                acc[0][c] = __builtin_fmaf(a0[0], b[c], acc[0][c]);
                acc[1][c] = __builtin_fmaf(a0[1], b[c], acc[1][c]);
                acc[2][c] = __builtin_fmaf(a0[2], b[c], acc[2][c]);
                acc[3][c] = __builtin_fmaf(a0[3], b[c], acc[3][c]);
                acc[4][c] = __builtin_fmaf(a1[0], b[c], acc[4][c]);
                acc[5][c] = __builtin_fmaf(a1[1], b[c], acc[5][c]);
                acc[6][c] = __builtin_fmaf(a1[2], b[c], acc[6][c]);
                acc[7][c] = __builtin_fmaf(a1[3], b[c], acc[7][c]);
            }
        }
        __syncthreads();
    }

#pragma unroll
    for (int r = 0; r < 8; ++r) {
        const int m  = bm * 128 + mt + r;
        const int bb = m >> 12, s = m & 4095;
#pragma unroll
        for (int c = 0; c < 4; ++c) {
            const int n  = bn * 64 + nt + c;
            const int hh = n >> 6, d = n & 63;
            qk_out[(((size_t)(bb * 16 + hh)) * 4096 + s) * 64 + d] = acc[r][c];
        }
    }
}

// ---------------------------------------------------------------------------
// Kernel 1b: v projection, fp32 sequential FMA -> bf16 [B,H,S,D].
// ---------------------------------------------------------------------------
__global__ __launch_bounds__(256)
void gemm_v(const float* __restrict__ hidden,
            const float* __restrict__ wv,
            unsigned short* __restrict__ v_out)
{
    __shared__ float As[16][132];
    __shared__ float Bs[16][68];
    const int tid = threadIdx.x;
    const int bm  = blockIdx.x;
    const int bn  = blockIdx.y;

    const float* Asrc = hidden + (size_t)bm * 128 * 1024;
    const float* Bsrc = wv + (size_t)bn * 64 * 1024;

    const int mt = (tid & 15) * 8;
    const int nt = (tid >> 4) * 4;

    float acc[8][4];
#pragma unroll
    for (int r = 0; r < 8; ++r)
#pragma unroll
        for (int c = 0; c < 4; ++c) acc[r][c] = 0.f;

    int arow[2], akof[2];
#pragma unroll
    for (int i = 0; i < 2; ++i) {
        const int c = i * 256 + tid;
        arow[i] = c >> 2;
        akof[i] = (c & 3) * 4;
    }
    const int brow = tid >> 2;
    const int bkof = (tid & 3) * 4;

    f32x4 apre[2], bpre;
#pragma unroll
    for (int i = 0; i < 2; ++i)
        apre[i] = *(const f32x4*)(Asrc + (size_t)arow[i] * 1024 + akof[i]);
    bpre = *(const f32x4*)(Bsrc + (size_t)brow * 1024 + bkof);

    for (int ks = 0; ks < 64; ++ks) {
#pragma unroll
        for (int i = 0; i < 2; ++i)
#pragma unroll
            for (int j = 0; j < 4; ++j)
                As[akof[i] + j][arow[i]] = apre[i][j];
#pragma unroll
        for (int j = 0; j < 4; ++j)
            Bs[bkof + j][brow] = bpre[j];
        __syncthreads();
        if (ks < 63) {
            const int k0 = (ks + 1) * 16;
#pragma unroll
            for (int i = 0; i < 2; ++i)
                apre[i] = *(const f32x4*)(Asrc + (size_t)arow[i] * 1024 + k0 + akof[i]);
            bpre = *(const f32x4*)(Bsrc + (size_t)brow * 1024 + k0 + bkof);
        }
#pragma unroll
        for (int k = 0; k < 16; ++k) {
            f32x4 a0 = *(const f32x4*)&As[k][mt];
            f32x4 a1 = *(const f32x4*)&As[k][mt + 4];
            f32x4 b  = *(const f32x4*)&Bs[k][nt];
#pragma unroll
            for (int c = 0; c < 4; ++c) {
                acc[0][c] = __builtin_fmaf(a0[0], b[c], acc[0][c]);
                acc[1][c] = __builtin_fmaf(a0[1], b[c], acc[1][c]);
                acc[2][c] = __builtin_fmaf(a0[2], b[c], acc[2][c]);
                acc[3][c] = __builtin_fmaf(a0[3], b[c], acc[3][c]);
                acc[4][c] = __builtin_fmaf(a1[0], b[c], acc[4][c]);
                acc[5][c] = __builtin_fmaf(a1[1], b[c], acc[5][c]);
                acc[6][c] = __builtin_fmaf(a1[2], b[c], acc[6][c]);
                acc[7][c] = __builtin_fmaf(a1[3], b[c], acc[7][c]);
            }
        }
        __syncthreads();
    }

#pragma unroll
    for (int r = 0; r < 8; ++r) {
        const int m  = bm * 128 + mt + r;
        const int bb = m >> 12, s = m & 4095;
#pragma unroll
        for (int c = 0; c < 4; ++c) {
            const int n  = bn * 64 + nt + c;
            const int hh = n >> 6, d = n & 63;
            v_out[(((size_t)(bb * 16 + hh)) * 4096 + s) * 64 + d] = f2bf(acc[r][c]);
        }
    }
}

// ---------------------------------------------------------------------------
// Kernel 2: hashing. rotated[n,r] = sequential ascending-d fp32 FMA of
// qk[row,d]*rot[d,n,r]. argmax over concat(rot,-rot) with np first-occurrence
// tie semantics. One wave per row-group; lanes = 64 r-columns.
// ---------------------------------------------------------------------------
__global__ __launch_bounds__(256)
void hash_kernel(const float* __restrict__ qk,
                 const float* __restrict__ rotf,
                 int* __restrict__ buckets)
{
    __shared__ float rot[8192];       // [d][n*64+r]
    __shared__ float rows[64 * 64];
    const int tid = threadIdx.x;
    for (int i = tid; i < 8192; i += 256) rot[i] = rotf[i];
    const int rbase = blockIdx.x * 64;
    {
        const f32x4* src = (const f32x4*)(qk + (size_t)rbase * 64);
        f32x4* dst = (f32x4*)rows;
#pragma unroll
        for (int i = 0; i < 4; ++i) dst[tid + i * 256] = src[tid + i * 256];
    }
    __syncthreads();
    const int w = tid >> 6, lane = tid & 63;
    for (int rr = 0; rr < 16; ++rr) {
        const int row = w * 16 + rr;
        float a0 = 0.f, a1 = 0.f;
#pragma unroll
        for (int dg = 0; dg < 16; ++dg) {
            f32x4 qb = *(const f32x4*)&rows[row * 64 + dg * 4];
#pragma unroll
            for (int j = 0; j < 4; ++j) {     // d = dg*4+j ascending
                const int d = dg * 4 + j;
                a0 = __builtin_fmaf(qb[j], rot[d * 128 + lane],      a0);
                a1 = __builtin_fmaf(qb[j], rot[d * 128 + 64 + lane], a1);
            }
        }
        // argmax over [ +a (idx=lane), -a (idx=64+lane) ], first-occurrence
        float v0, v1; int i0, i1;
        if (a0 >= -a0) { v0 = a0;  i0 = lane; } else { v0 = -a0; i0 = 64 + lane; }
        if (a1 >= -a1) { v1 = a1;  i1 = lane; } else { v1 = -a1; i1 = 64 + lane; }
#pragma unroll
        for (int m = 1; m < 64; m <<= 1) {
            float ov = __shfl_xor(v0, m); int oi = __shfl_xor(i0, m);
            if (ov > v0 || (ov == v0 && oi < i0)) { v0 = ov; i0 = oi; }
            ov = __shfl_xor(v1, m); oi = __shfl_xor(i1, m);
            if (ov > v1 || (ov == v1 && oi < i1)) { v1 = ov; i1 = oi; }
        }
        if (lane == 0) {
            const int g = rbase + row;
            const int bh = g >> 12, s = g & 4095;
            buckets[(size_t)bh * 8192 + s]        = i0;          // hash 0
            buckets[(size_t)bh * 8192 + 4096 + s] = i1 + 128;    // hash 1
        }
    }
}

// ---------------------------------------------------------------------------
// Kernel 3: stable counting sort per (b,h) by (bucket, position).
// ---------------------------------------------------------------------------
__global__ __launch_bounds__(256)
void sort_kernel(const int* __restrict__ buckets, int* __restrict__ sorted)
{
    __shared__ unsigned char  lb[8192];
    __shared__ unsigned short sl[8192];
    __shared__ int cnt[256];
    const int tid = threadIdx.x;
    const int bh  = blockIdx.x;
    cnt[tid] = 0;
    for (int i = tid; i < 8192; i += 256)
        lb[i] = (unsigned char)buckets[(size_t)bh * 8192 + i];
    __syncthreads();
    for (int i = tid; i < 8192; i += 256) atomicAdd(&cnt[lb[i]], 1);
    __syncthreads();
    int mybase = 0;
    for (int v = 0; v < 256; ++v) { int cv = cnt[v]; if (v < tid) mybase += cv; }
    int c = 0;
    for (int i = 0; i < 8192; ++i) {
        if ((int)lb[i] == tid) { sl[mybase + c] = (unsigned short)i; ++c; }
    }
    __syncthreads();
    for (int i = tid; i < 8192; i += 256)
        sorted[(size_t)bh * 8192 + i] = (int)sl[i];
}

// ---------------------------------------------------------------------------
// Kernel 4a: phase A — per-hash logits (logsumexp over 128 keys with masks).
// ---------------------------------------------------------------------------
__global__ __launch_bounds__(256)
void attn_logits(const float* __restrict__ qk,
                 const int* __restrict__ sorted,
                 float* __restrict__ logits)
{
    __shared__ float kk[128 * 68];
    __shared__ float scl[128];
    __shared__ int   stick[128];
    __shared__ int   qtick[64];
    __shared__ float red[512];
    const int tid = threadIdx.x;
    const int c  = blockIdx.x;
    const int bh = blockIdx.z * 16 + blockIdx.y;
    const int pc = (c + 127) & 127;

    if (tid < 128) {
        const int p  = (tid < 64) ? (pc * 64 + tid) : (c * 64 + (tid - 64));
        const int tk = sorted[(size_t)bh * 8192 + p];
        stick[tid] = tk & 4095;
        if (tid >= 64) qtick[tid - 64] = tk;
    }
    __syncthreads();
    {
        const int r = tid >> 1, half = tid & 1;
        const int srow = stick[r];
        const f32x4* src = (const f32x4*)(qk + (((size_t)bh * 4096 + srow) << 6) + half * 32);
#pragma unroll
        for (int i = 0; i < 8; ++i)
            *(f32x4*)&kk[r * 68 + half * 32 + i * 4] = src[i];
    }
    __syncthreads();
    if (tid < 128) {
        float ss = 0.f;
#pragma unroll
        for (int dg = 0; dg < 16; ++dg) {
            f32x4 x = *(const f32x4*)&kk[tid * 68 + dg * 4];
            ss += x[0]*x[0] + x[1]*x[1] + x[2]*x[2] + x[3]*x[3];
        }
        scl[tid] = (1.0f / sqrtf(ss * (1.0f / 64.0f) + 1e-6f)) * 0.125f;
    }
    __syncthreads();

    const int q = tid & 63, kb = tid >> 6;
    float qreg[64];
#pragma unroll
    for (int dg = 0; dg < 16; ++dg) {
        f32x4 x = *(const f32x4*)&kk[(64 + q) * 68 + dg * 4];
        qreg[dg*4+0] = x[0]; qreg[dg*4+1] = x[1]; qreg[dg*4+2] = x[2]; qreg[dg*4+3] = x[3];
    }
    const int tq = stick[64 + q];

    float dots[32];
#pragma unroll
    for (int j = 0; j < 32; ++j) {
        const int k = kb * 32 + j;
        float a = 0.f;
#pragma unroll
        for (int dg = 0; dg < 16; ++dg) {
            f32x4 kv = *(const f32x4*)&kk[k * 68 + dg * 4];
            a += qreg[dg*4+0]*kv[0] + qreg[dg*4+1]*kv[1]
               + qreg[dg*4+2]*kv[2] + qreg[dg*4+3]*kv[3];
        }
        a *= scl[k];
        const int tk = stick[k];
        if (tq < tk)  a = -1e9f;
        if (tq == tk) a = -1e5f;
        dots[j] = a;
    }

    float mloc = -3.4e38f;
#pragma unroll
    for (int j = 0; j < 32; ++j) mloc = fmaxf(mloc, dots[j]);
    red[kb * 64 + q] = mloc;
    __syncthreads();
    const float M = fmaxf(fmaxf(red[q], red[64 + q]), fmaxf(red[128 + q], red[192 + q]));
    float l = 0.f;
#pragma unroll
    for (int j = 0; j < 32; ++j) l += expf(dots[j] - M);
    red[256 + kb * 64 + q] = l;
    __syncthreads();
    if (tid < 64) {
        const float L = red[256 + tid] + red[320 + tid] + red[384 + tid] + red[448 + tid];
        const float Mq = fmaxf(fmaxf(red[tid], red[64 + tid]), fmaxf(red[128 + tid], red[192 + tid]));
        const float logit = Mq + logf(L);
        const int tk = qtick[tid];
        logits[((size_t)bh * 2 + (tk >> 12)) * 4096 + (tk & 4095)] = logit;
    }
}

// ---------------------------------------------------------------------------
// Kernel 4b: phase B — probs = exp(dots - stored own-logit); per-hash output;
// combine weight from both stored logits; atomicAdd w*o into d_out (fp32).
// ---------------------------------------------------------------------------
__global__ __launch_bounds__(256)
void attn_out(const float* __restrict__ qk,
              const unsigned short* __restrict__ vb,
              const int* __restrict__ sorted,
              const float* __restrict__ logits,
              float* __restrict__ out)
{
    __shared__ float          kk[128 * 68];
    __shared__ unsigned short vv[128 * 64];
    __shared__ float scl[128];
    __shared__ int   stick[128];
    __shared__ int   qtick[64];
    const int tid = threadIdx.x;
    const int c  = blockIdx.x;
    const int bh = blockIdx.z * 16 + blockIdx.y;
    const int pc = (c + 127) & 127;

    if (tid < 128) {
        const int p  = (tid < 64) ? (pc * 64 + tid) : (c * 64 + (tid - 64));
        const int tk = sorted[(size_t)bh * 8192 + p];
        stick[tid] = tk & 4095;
        if (tid >= 64) qtick[tid - 64] = tk;
    }
    __syncthreads();
    {
        const int r = tid >> 1, half = tid & 1;
        const int srow = stick[r];
        const f32x4* src = (const f32x4*)(qk + (((size_t)bh * 4096 + srow) << 6) + half * 32);
#pragma unroll
        for (int i = 0; i < 8; ++i)
            *(f32x4*)&kk[r * 68 + half * 32 + i * 4] = src[i];
        const unsigned short* vs = vb + (((size_t)bh * 4096 + srow) << 6) + half * 32;
#pragma unroll
        for (int i = 0; i < 4; ++i)
            *(u16x8*)&vv[r * 64 + half * 32 + i * 8] = *(const u16x8*)(vs + i * 8);
    }
    __syncthreads();
    if (tid < 128) {
        float ss = 0.f;
#pragma unroll
        for (int dg = 0; dg < 16; ++dg) {
            f32x4 x = *(const f32x4*)&kk[tid * 68 + dg * 4];
            ss += x[0]*x[0] + x[1]*x[1] + x[2]*x[2] + x[3]*x[3];
        }
        scl[tid] = (1.0f / sqrtf(ss * (1.0f / 64.0f) + 1e-6f)) * 0.125f;
    }
    __syncthreads();

    const int q = tid & 63, kb = tid >> 6;
    float qreg[64];
#pragma unroll
    for (int dg = 0; dg < 16; ++dg) {
        f32x4 x = *(const f32x4*)&kk[(64 + q) * 68 + dg * 4];
        qreg[dg*4+0] = x[0]; qreg[dg*4+1] = x[1]; qreg[dg*4+2] = x[2]; qreg[dg*4+3] = x[3];
    }
    const int tq = stick[64 + q];
    const int tkq = qtick[q];
    const float lgq = logits[((size_t)bh * 2 + (tkq >> 12)) * 4096 + (tkq & 4095)];

    float dots[32];
#pragma unroll
    for (int j = 0; j < 32; ++j) {
        const int k = kb * 32 + j;
        float a = 0.f;
#pragma unroll
        for (int dg = 0; dg < 16; ++dg) {
            f32x4 kv = *(const f32x4*)&kk[k * 68 + dg * 4];
            a += qreg[dg*4+0]*kv[0] + qreg[dg*4+1]*kv[1]
               + qreg[dg*4+2]*kv[2] + qreg[dg*4+3]*kv[3];
        }
        a *= scl[k];
        const int tk = stick[k];
        if (tq < tk)  a = -1e9f;
        if (tq == tk) a = -1e5f;
        dots[j] = expf(a - lgq);        // probs
    }

    float o[64];
#pragma unroll
    for (int i = 0; i < 64; ++i) o[i] = 0.f;
#pragma unroll
    for (int j = 0; j < 32; ++j) {
        const float p = dots[j];
        const int k = kb * 32 + j;
#pragma unroll
        for (int dg = 0; dg < 8; ++dg) {
            u16x8 vx = *(const u16x8*)&vv[k * 64 + dg * 8];
#pragma unroll
            for (int e = 0; e < 8; ++e) o[dg * 8 + e] += p * bf2f(vx[e]);
        }
    }
    __syncthreads();                 // all kk reads complete; reuse as outbuf
    float* outb = kk;                // pitch 68
#pragma unroll
    for (int rs = 0; rs < 4; ++rs) {
        if (kb == rs) {
#pragma unroll
            for (int dg = 0; dg < 16; ++dg) {
                f32x4 val = {o[dg*4+0], o[dg*4+1], o[dg*4+2], o[dg*4+3]};
                f32x4* dst = (f32x4*)&outb[q * 68 + dg * 4];
                if (rs == 0) *dst = val;
                else { f32x4 old = *dst; *dst = old + val; }
            }
        }
        __syncthreads();
    }

    {
        const int qq = tid >> 2, part = tid & 3;
        const int tk = qtick[qq];
        const int n  = tk >> 12, s = tk & 4095;
        const float lg0 = logits[((size_t)bh * 2 + 0) * 4096 + s];
        const float lg1 = logits[((size_t)bh * 2 + 1) * 4096 + s];
        const float m  = fmaxf(lg0, lg1);
        const float e0 = expf(lg0 - m), e1 = expf(lg1 - m);
        const float w  = ((n == 0) ? e0 : e1) / (e0 + e1);
        const int b = bh >> 4, hh = bh & 15;
        float* dst = out + ((size_t)b * 4096 + s) * 1024 + hh * 64 + part * 16;
#pragma unroll
        for (int i = 0; i < 16; ++i)
            atomicAdd(&dst[i], w * outb[qq * 68 + part * 16 + i]);
    }
}

// ---------------------------------------------------------------------------
extern "C" void kernel_launch(void* const* d_in, const int* in_sizes, int n_in,
                              void* d_out, int out_size, void* d_ws, size_t ws_size,
                              hipStream_t stream) {
    const float* hidden = (const float*)d_in[0];   // [2,4096,1024] fp32
    const float* wqk    = (const float*)d_in[1];   // [1024,1024]   fp32
    const float* wv     = (const float*)d_in[2];   // [1024,1024]   fp32
    const float* rotf   = (const float*)d_in[3];   // [64,2,64]     fp32
    float* out = (float*)d_out;                    // [2,4096,1024] fp32

    char* ws = (char*)d_ws;
    float*          qk      = (float*)(ws);                       // 33,554,432 B
    unsigned short* vb      = (unsigned short*)(ws + 33554432);   // 16,777,216 B
    int*            buckets = (int*)(ws + 50331648);              //  1,048,576 B
    int*            sorted  = (int*)(ws + 51380224);              //  1,048,576 B
    float*          logits  = (float*)(ws + 52428800);            //  1,048,576 B
    // total 53,477,376 B (51 MB)

    hipMemsetAsync(d_out, 0, (size_t)out_size * sizeof(float), stream);

    hipLaunchKernelGGL(gemm_qk,     dim3(64, 16),     dim3(256), 0, stream,
                       hidden, wqk, qk);
    hipLaunchKernelGGL(gemm_v,      dim3(64, 16),     dim3(256), 0, stream,
                       hidden, wv, vb);
    hipLaunchKernelGGL(hash_kernel, dim3(2048),       dim3(256), 0, stream,
                       qk, rotf, buckets);
    hipLaunchKernelGGL(sort_kernel, dim3(32),         dim3(256), 0, stream,
                       buckets, sorted);
    hipLaunchKernelGGL(attn_logits, dim3(128, 16, 2), dim3(256), 0, stream,
                       qk, sorted, logits);
    hipLaunchKernelGGL(attn_out,    dim3(128, 16, 2), dim3(256), 0, stream,
                       qk, vb, sorted, logits, out);
}

// Round 7
// 1497.576 us; speedup vs baseline: 1.5754x; 1.5754x over previous
//
#include <hip/hip_runtime.h>

// ---------------------------------------------------------------------------
// LSH self-attention (Reformer). B=2,S=4096,H=16,D=64,NH=2,NB=128,CHUNK=64,
// N_BEFORE=1. Inputs fp32, output fp32.
// Precision-critical path (qk projection + rotated einsum feeding argmax) is
// fp32 with sequential ascending-k FMA chains (matches np/BLAS order; verified
// PASS in round 6). Attention: single pass per (bh,chunk), per-hash bf16
// output stored scattered (no atomics), then coalesced softmax-combine.
// ---------------------------------------------------------------------------

typedef __attribute__((ext_vector_type(4))) float          f32x4;
typedef __attribute__((ext_vector_type(4))) unsigned short u16x4;
typedef __attribute__((ext_vector_type(8))) unsigned short u16x8;

__device__ __forceinline__ float bf2f(unsigned short u) {
    unsigned int x = ((unsigned int)u) << 16;
    return __builtin_bit_cast(float, x);
}
__device__ __forceinline__ unsigned short f2bf(float f) {
    unsigned int x = __builtin_bit_cast(unsigned int, f);
    x += 0x7FFFu + ((x >> 16) & 1u);
    return (unsigned short)(x >> 16);
}

// ---------------------------------------------------------------------------
// Kernel 1a: qk projection. fp32, sequential ascending-k FMA. [B,H,S,D] fp32.
// ---------------------------------------------------------------------------
__global__ __launch_bounds__(256)
void gemm_qk(const float* __restrict__ hidden,
             const float* __restrict__ wqk,
             float* __restrict__ qk_out)
{
    __shared__ float As[16][132];
    __shared__ float Bs[16][68];
    const int tid = threadIdx.x;
    const int bm  = blockIdx.x;     // 0..63
    const int bn  = blockIdx.y;     // 0..15

    const float* Asrc = hidden + (size_t)bm * 128 * 1024;
    const float* Bsrc = wqk + (size_t)bn * 64 * 1024;

    const int mt = (tid & 15) * 8;
    const int nt = (tid >> 4) * 4;

    float acc[8][4];
#pragma unroll
    for (int r = 0; r < 8; ++r)
#pragma unroll
        for (int c = 0; c < 4; ++c) acc[r][c] = 0.f;

    int arow[2], akof[2];
#pragma unroll
    for (int i = 0; i < 2; ++i) {
        const int c = i * 256 + tid;
        arow[i] = c >> 2;
        akof[i] = (c & 3) * 4;
    }
    const int brow = tid >> 2;
    const int bkof = (tid & 3) * 4;

    f32x4 apre[2], bpre;
#pragma unroll
    for (int i = 0; i < 2; ++i)
        apre[i] = *(const f32x4*)(Asrc + (size_t)arow[i] * 1024 + akof[i]);
    bpre = *(const f32x4*)(Bsrc + (size_t)brow * 1024 + bkof);

    for (int ks = 0; ks < 64; ++ks) {     // K = 64 tiles * 16, ascending
#pragma unroll
        for (int i = 0; i < 2; ++i)
#pragma unroll
            for (int j = 0; j < 4; ++j)
                As[akof[i] + j][arow[i]] = apre[i][j];
#pragma unroll
        for (int j = 0; j < 4; ++j)
            Bs[bkof + j][brow] = bpre[j];
        __syncthreads();
        if (ks < 63) {
            const int k0 = (ks + 1) * 16;
#pragma unroll
            for (int i = 0; i < 2; ++i)
                apre[i] = *(const f32x4*)(Asrc + (size_t)arow[i] * 1024 + k0 + akof[i]);
            bpre = *(const f32x4*)(Bsrc + (size_t)brow * 1024 + k0 + bkof);
        }
#pragma unroll
        for (int k = 0; k < 16; ++k) {
            f32x4 a0 = *(const f32x4*)&As[k][mt];
            f32x4 a1 = *(const f32x4*)&As[k][mt + 4];
            f32x4 b  = *(const f32x4*)&Bs[k][nt];
#pragma unroll
            for (int c = 0; c < 4; ++c) {
                acc[0][c] = __builtin_fmaf(a0[0], b[c], acc[0][c]);
                acc[1][c] = __builtin_fmaf(a0[1], b[c], acc[1][c]);
                acc[2][c] = __builtin_fmaf(a0[2], b[c], acc[2][c]);
                acc[3][c] = __builtin_fmaf(a0[3], b[c], acc[3][c]);
                acc[4][c] = __builtin_fmaf(a1[0], b[c], acc[4][c]);
                acc[5][c] = __builtin_fmaf(a1[1], b[c], acc[5][c]);
                acc[6][c] = __builtin_fmaf(a1[2], b[c], acc[6][c]);
                acc[7][c] = __builtin_fmaf(a1[3], b[c], acc[7][c]);
            }
        }
        __syncthreads();
    }

#pragma unroll
    for (int r = 0; r < 8; ++r) {
        const int m  = bm * 128 + mt + r;
        const int bb = m >> 12, s = m & 4095;
#pragma unroll
        for (int c = 0; c < 4; ++c) {
            const int n  = bn * 64 + nt + c;
            const int hh = n >> 6, d = n & 63;
            qk_out[(((size_t)(bb * 16 + hh)) * 4096 + s) * 64 + d] = acc[r][c];
        }
    }
}

// ---------------------------------------------------------------------------
// Kernel 1b: v projection, fp32 sequential FMA -> bf16 [B,H,S,D].
// ---------------------------------------------------------------------------
__global__ __launch_bounds__(256)
void gemm_v(const float* __restrict__ hidden,
            const float* __restrict__ wv,
            unsigned short* __restrict__ v_out)
{
    __shared__ float As[16][132];
    __shared__ float Bs[16][68];
    const int tid = threadIdx.x;
    const int bm  = blockIdx.x;
    const int bn  = blockIdx.y;

    const float* Asrc = hidden + (size_t)bm * 128 * 1024;
    const float* Bsrc = wv + (size_t)bn * 64 * 1024;

    const int mt = (tid & 15) * 8;
    const int nt = (tid >> 4) * 4;

    float acc[8][4];
#pragma unroll
    for (int r = 0; r < 8; ++r)
#pragma unroll
        for (int c = 0; c < 4; ++c) acc[r][c] = 0.f;

    int arow[2], akof[2];
#pragma unroll
    for (int i = 0; i < 2; ++i) {
        const int c = i * 256 + tid;
        arow[i] = c >> 2;
        akof[i] = (c & 3) * 4;
    }
    const int brow = tid >> 2;
    const int bkof = (tid & 3) * 4;

    f32x4 apre[2], bpre;
#pragma unroll
    for (int i = 0; i < 2; ++i)
        apre[i] = *(const f32x4*)(Asrc + (size_t)arow[i] * 1024 + akof[i]);
    bpre = *(const f32x4*)(Bsrc + (size_t)brow * 1024 + bkof);

    for (int ks = 0; ks < 64; ++ks) {
#pragma unroll
        for (int i = 0; i < 2; ++i)
#pragma unroll
            for (int j = 0; j < 4; ++j)
                As[akof[i] + j][arow[i]] = apre[i][j];
#pragma unroll
        for (int j = 0; j < 4; ++j)
            Bs[bkof + j][brow] = bpre[j];
        __syncthreads();
        if (ks < 63) {
            const int k0 = (ks + 1) * 16;
#pragma unroll
            for (int i = 0; i < 2; ++i)
                apre[i] = *(const f32x4*)(Asrc + (size_t)arow[i] * 1024 + k0 + akof[i]);
            bpre = *(const f32x4*)(Bsrc + (size_t)brow * 1024 + k0 + bkof);
        }
#pragma unroll
        for (int k = 0; k < 16; ++k) {
            f32x4 a0 = *(const f32x4*)&As[k][mt];
            f32x4 a1 = *(const f32x4*)&As[k][mt + 4];
            f32x4 b  = *(const f32x4*)&Bs[k][nt];
#pragma unroll
            for (int c = 0; c < 4; ++c) {
                acc[0][c] = __builtin_fmaf(a0[0], b[c], acc[0][c]);
                acc[1][c] = __builtin_fmaf(a0[1], b[c], acc[1][c]);
                acc[2][c] = __builtin_fmaf(a0[2], b[c], acc[2][c]);
                acc[3][c] = __builtin_fmaf(a0[3], b[c], acc[3][c]);
                acc[4][c] = __builtin_fmaf(a1[0], b[c], acc[4][c]);
                acc[5][c] = __builtin_fmaf(a1[1], b[c], acc[5][c]);
                acc[6][c] = __builtin_fmaf(a1[2], b[c], acc[6][c]);
                acc[7][c] = __builtin_fmaf(a1[3], b[c], acc[7][c]);
            }
        }
        __syncthreads();
    }

#pragma unroll
    for (int r = 0; r < 8; ++r) {
        const int m  = bm * 128 + mt + r;
        const int bb = m >> 12, s = m & 4095;
#pragma unroll
        for (int c = 0; c < 4; ++c) {
            const int n  = bn * 64 + nt + c;
            const int hh = n >> 6, d = n & 63;
            v_out[(((size_t)(bb * 16 + hh)) * 4096 + s) * 64 + d] = f2bf(acc[r][c]);
        }
    }
}

// ---------------------------------------------------------------------------
// Kernel 2: hashing. Sequential ascending-d fp32 FMA; argmax over
// concat(rot,-rot), first-occurrence ties. One wave per row-group.
// ---------------------------------------------------------------------------
__global__ __launch_bounds__(256)
void hash_kernel(const float* __restrict__ qk,
                 const float* __restrict__ rotf,
                 int* __restrict__ buckets)
{
    __shared__ float rot[8192];       // [d][n*64+r]
    __shared__ float rows[64 * 64];
    const int tid = threadIdx.x;
    for (int i = tid; i < 8192; i += 256) rot[i] = rotf[i];
    const int rbase = blockIdx.x * 64;
    {
        const f32x4* src = (const f32x4*)(qk + (size_t)rbase * 64);
        f32x4* dst = (f32x4*)rows;
#pragma unroll
        for (int i = 0; i < 4; ++i) dst[tid + i * 256] = src[tid + i * 256];
    }
    __syncthreads();
    const int w = tid >> 6, lane = tid & 63;
    for (int rr = 0; rr < 16; ++rr) {
        const int row = w * 16 + rr;
        float a0 = 0.f, a1 = 0.f;
#pragma unroll
        for (int dg = 0; dg < 16; ++dg) {
            f32x4 qb = *(const f32x4*)&rows[row * 64 + dg * 4];
#pragma unroll
            for (int j = 0; j < 4; ++j) {
                const int d = dg * 4 + j;
                a0 = __builtin_fmaf(qb[j], rot[d * 128 + lane],      a0);
                a1 = __builtin_fmaf(qb[j], rot[d * 128 + 64 + lane], a1);
            }
        }
        float v0, v1; int i0, i1;
        if (a0 >= -a0) { v0 = a0;  i0 = lane; } else { v0 = -a0; i0 = 64 + lane; }
        if (a1 >= -a1) { v1 = a1;  i1 = lane; } else { v1 = -a1; i1 = 64 + lane; }
#pragma unroll
        for (int m = 1; m < 64; m <<= 1) {
            float ov = __shfl_xor(v0, m); int oi = __shfl_xor(i0, m);
            if (ov > v0 || (ov == v0 && oi < i0)) { v0 = ov; i0 = oi; }
            ov = __shfl_xor(v1, m); oi = __shfl_xor(i1, m);
            if (ov > v1 || (ov == v1 && oi < i1)) { v1 = ov; i1 = oi; }
        }
        if (lane == 0) {
            const int g = rbase + row;
            const int bh = g >> 12, s = g & 4095;
            buckets[(size_t)bh * 8192 + s]        = i0;          // hash 0
            buckets[(size_t)bh * 8192 + 4096 + s] = i1 + 128;    // hash 1
        }
    }
}

// ---------------------------------------------------------------------------
// Kernel 3: stable counting sort per (b,h) by (bucket, position).
// ---------------------------------------------------------------------------
__global__ __launch_bounds__(256)
void sort_kernel(const int* __restrict__ buckets, int* __restrict__ sorted)
{
    __shared__ unsigned char  lb[8192];
    __shared__ unsigned short sl[8192];
    __shared__ int cnt[256];
    const int tid = threadIdx.x;
    const int bh  = blockIdx.x;
    cnt[tid] = 0;
    for (int i = tid; i < 8192; i += 256)
        lb[i] = (unsigned char)buckets[(size_t)bh * 8192 + i];
    __syncthreads();
    for (int i = tid; i < 8192; i += 256) atomicAdd(&cnt[lb[i]], 1);
    __syncthreads();
    int mybase = 0;
    for (int v = 0; v < 256; ++v) { int cv = cnt[v]; if (v < tid) mybase += cv; }
    int c = 0;
    for (int i = 0; i < 8192; ++i) {
        if ((int)lb[i] == tid) { sl[mybase + c] = (unsigned short)i; ++c; }
    }
    __syncthreads();
    for (int i = tid; i < 8192; i += 256)
        sorted[(size_t)bh * 8192 + i] = (int)sl[i];
}

// ---------------------------------------------------------------------------
// Kernel 4: fused chunked attention. One block per (b,h,chunk): dots ->
// logsumexp -> probs -> PV in one pass. Writes per-hash out (bf16, plain
// scattered 256B stores, NO atomics) + logits.
// ---------------------------------------------------------------------------
__global__ __launch_bounds__(256)
void attn_kernel(const float* __restrict__ qk,
                 const unsigned short* __restrict__ vb,
                 const int* __restrict__ sorted,
                 unsigned short* __restrict__ out_hash,
                 float* __restrict__ logits)
{
    __shared__ float          kk[128 * 68];
    __shared__ unsigned short vv[128 * 64];
    __shared__ float scl[128];
    __shared__ int   stick[128];
    __shared__ int   qtick[64];
    __shared__ float red[512];
    const int tid = threadIdx.x;
    const int c  = blockIdx.x;
    const int bh = blockIdx.z * 16 + blockIdx.y;
    const int pc = (c + 127) & 127;

    if (tid < 128) {
        const int p  = (tid < 64) ? (pc * 64 + tid) : (c * 64 + (tid - 64));
        const int tk = sorted[(size_t)bh * 8192 + p];
        stick[tid] = tk & 4095;
        if (tid >= 64) qtick[tid - 64] = tk;
    }
    __syncthreads();
    {
        const int r = tid >> 1, half = tid & 1;
        const int srow = stick[r];
        const f32x4* src = (const f32x4*)(qk + (((size_t)bh * 4096 + srow) << 6) + half * 32);
#pragma unroll
        for (int i = 0; i < 8; ++i)
            *(f32x4*)&kk[r * 68 + half * 32 + i * 4] = src[i];
        const unsigned short* vs = vb + (((size_t)bh * 4096 + srow) << 6) + half * 32;
#pragma unroll
        for (int i = 0; i < 4; ++i)
            *(u16x8*)&vv[r * 64 + half * 32 + i * 8] = *(const u16x8*)(vs + i * 8);
    }
    __syncthreads();
    if (tid < 128) {
        float ss = 0.f;
#pragma unroll
        for (int dg = 0; dg < 16; ++dg) {
            f32x4 x = *(const f32x4*)&kk[tid * 68 + dg * 4];
            ss += x[0]*x[0] + x[1]*x[1] + x[2]*x[2] + x[3]*x[3];
        }
        scl[tid] = (1.0f / sqrtf(ss * (1.0f / 64.0f) + 1e-6f)) * 0.125f;
    }
    __syncthreads();

    const int q = tid & 63, kb = tid >> 6;
    float qreg[64];
#pragma unroll
    for (int dg = 0; dg < 16; ++dg) {
        f32x4 x = *(const f32x4*)&kk[(64 + q) * 68 + dg * 4];
        qreg[dg*4+0] = x[0]; qreg[dg*4+1] = x[1]; qreg[dg*4+2] = x[2]; qreg[dg*4+3] = x[3];
    }
    const int tq = stick[64 + q];

    float dots[32];
#pragma unroll
    for (int j = 0; j < 32; ++j) {
        const int k = kb * 32 + j;
        float a = 0.f;
#pragma unroll
        for (int dg = 0; dg < 16; ++dg) {
            f32x4 kv = *(const f32x4*)&kk[k * 68 + dg * 4];
            a += qreg[dg*4+0]*kv[0] + qreg[dg*4+1]*kv[1]
               + qreg[dg*4+2]*kv[2] + qreg[dg*4+3]*kv[3];
        }
        a *= scl[k];
        const int tk = stick[k];
        if (tq < tk)  a = -1e9f;
        if (tq == tk) a = -1e5f;
        dots[j] = a;
    }

    float mloc = -3.4e38f;
#pragma unroll
    for (int j = 0; j < 32; ++j) mloc = fmaxf(mloc, dots[j]);
    red[kb * 64 + q] = mloc;
    __syncthreads();
    const float M = fmaxf(fmaxf(red[q], red[64 + q]), fmaxf(red[128 + q], red[192 + q]));
    float l = 0.f;
#pragma unroll
    for (int j = 0; j < 32; ++j) l += expf(dots[j] - M);
    red[256 + kb * 64 + q] = l;
    __syncthreads();
    const float L = red[256 + q] + red[320 + q] + red[384 + q] + red[448 + q];
    const float logit = M + logf(L);
#pragma unroll
    for (int j = 0; j < 32; ++j) dots[j] = expf(dots[j] - logit);   // probs

    float o[64];
#pragma unroll
    for (int i = 0; i < 64; ++i) o[i] = 0.f;
#pragma unroll
    for (int j = 0; j < 32; ++j) {
        const float p = dots[j];
        const int k = kb * 32 + j;
#pragma unroll
        for (int dg = 0; dg < 8; ++dg) {
            u16x8 vx = *(const u16x8*)&vv[k * 64 + dg * 8];
#pragma unroll
            for (int e = 0; e < 8; ++e) o[dg * 8 + e] += p * bf2f(vx[e]);
        }
    }
    __syncthreads();                 // all kk reads complete; reuse as outbuf
    float* outb = kk;                // pitch 68
#pragma unroll
    for (int rs = 0; rs < 4; ++rs) {
        if (kb == rs) {
#pragma unroll
            for (int dg = 0; dg < 16; ++dg) {
                f32x4 val = {o[dg*4+0], o[dg*4+1], o[dg*4+2], o[dg*4+3]};
                f32x4* dst = (f32x4*)&outb[q * 68 + dg * 4];
                if (rs == 0) *dst = val;
                else { f32x4 old = *dst; *dst = old + val; }
            }
        }
        __syncthreads();
    }

    if (tid < 64) {   // logit identical across kb for same q
        const int tk = qtick[tid];
        logits[((size_t)bh * 2 + (tk >> 12)) * 4096 + (tk & 4095)] = logit;
    }
    {
        const int qq = tid >> 2, part = tid & 3;
        const int tk = qtick[qq];
        const size_t ob = (((size_t)bh * 2 + (tk >> 12)) * 4096 + (tk & 4095)) * 64 + part * 16;
#pragma unroll
        for (int i = 0; i < 16; i += 4) {
            u16x4 uu;
            uu[0] = f2bf(outb[qq * 68 + part * 16 + i + 0]);
            uu[1] = f2bf(outb[qq * 68 + part * 16 + i + 1]);
            uu[2] = f2bf(outb[qq * 68 + part * 16 + i + 2]);
            uu[3] = f2bf(outb[qq * 68 + part * 16 + i + 3]);
            *(u16x4*)(out_hash + ob + i) = uu;
        }
    }
}

// ---------------------------------------------------------------------------
// Kernel 5: combine hash rounds with logsumexp weights; emit fp32 [B,S,H*D].
// Fully coalesced reads; writes in 256B chunks.
// ---------------------------------------------------------------------------
__global__ __launch_bounds__(256)
void combine_kernel(const unsigned short* __restrict__ out_hash,
                    const float* __restrict__ logits,
                    float* __restrict__ out)
{
    const int idx  = blockIdx.x * 256 + threadIdx.x;   // < 2097152
    const int bh   = idx >> 16;
    const int rem  = idx & 65535;
    const int s    = rem >> 4;
    const int part = rem & 15;
    const float lg0 = logits[((size_t)bh * 2 + 0) * 4096 + s];
    const float lg1 = logits[((size_t)bh * 2 + 1) * 4096 + s];
    const float m  = fmaxf(lg0, lg1);
    const float e0 = expf(lg0 - m), e1 = expf(lg1 - m);
    const float inv = 1.0f / (e0 + e1);
    const float w0 = e0 * inv, w1 = e1 * inv;
    const size_t b0 = (((size_t)bh * 2 + 0) * 4096 + s) * 64 + part * 4;
    const size_t b1 = (((size_t)bh * 2 + 1) * 4096 + s) * 64 + part * 4;
    u16x4 u0 = *(const u16x4*)(out_hash + b0);
    u16x4 u1 = *(const u16x4*)(out_hash + b1);
    const int b = bh >> 4, hh = bh & 15;
    const size_t ob = ((size_t)b * 4096 + s) * 1024 + hh * 64 + part * 4;
    f32x4 r;
#pragma unroll
    for (int e = 0; e < 4; ++e)
        r[e] = w0 * bf2f(u0[e]) + w1 * bf2f(u1[e]);
    *(f32x4*)(out + ob) = r;
}

// ---------------------------------------------------------------------------
extern "C" void kernel_launch(void* const* d_in, const int* in_sizes, int n_in,
                              void* d_out, int out_size, void* d_ws, size_t ws_size,
                              hipStream_t stream) {
    const float* hidden = (const float*)d_in[0];   // [2,4096,1024] fp32
    const float* wqk    = (const float*)d_in[1];   // [1024,1024]   fp32
    const float* wv     = (const float*)d_in[2];   // [1024,1024]   fp32
    const float* rotf   = (const float*)d_in[3];   // [64,2,64]     fp32
    float* out = (float*)d_out;                    // [2,4096,1024] fp32

    char* ws = (char*)d_ws;
    float*          qk       = (float*)(ws);                       // 33,554,432 B
    unsigned short* vb       = (unsigned short*)(ws + 33554432);   // 16,777,216 B
    int*            buckets  = (int*)(ws + 50331648);              //  1,048,576 B
    int*            sorted   = (int*)(ws + 51380224);              //  1,048,576 B
    float*          logits   = (float*)(ws + 52428800);            //  1,048,576 B
    unsigned short* out_hash = (unsigned short*)(ws + 53477376);   // 33,554,432 B
    // total 87,031,808 B (ws_size >= 88 MB proven by round-4/5 bit-identity)

    hipLaunchKernelGGL(gemm_qk,     dim3(64, 16),     dim3(256), 0, stream,
                       hidden, wqk, qk);
    hipLaunchKernelGGL(gemm_v,      dim3(64, 16),     dim3(256), 0, stream,
                       hidden, wv, vb);
    hipLaunchKernelGGL(hash_kernel, dim3(2048),       dim3(256), 0, stream,
                       qk, rotf, buckets);
    hipLaunchKernelGGL(sort_kernel, dim3(32),         dim3(256), 0, stream,
                       buckets, sorted);
    hipLaunchKernelGGL(attn_kernel, dim3(128, 16, 2), dim3(256), 0, stream,
                       qk, vb, sorted, out_hash, logits);
    hipLaunchKernelGGL(combine_kernel, dim3(8192),    dim3(256), 0, stream,
                       out_hash, logits, out);
}

// Round 8
// 1035.003 us; speedup vs baseline: 2.2795x; 1.4469x over previous
//
#include <hip/hip_runtime.h>

// ---------------------------------------------------------------------------
// LSH self-attention (Reformer). B=2,S=4096,H=16,D=64,NH=2,NB=128,CHUNK=64,
// N_BEFORE=1. Inputs fp32, output fp32.
// Precision-critical path (qk projection + rotated einsum feeding argmax) is
// fp32 with sequential ascending-k FMA chains (matches np/BLAS order; verified
// PASS rounds 6-7, absmax 0.015625). Sort: ballot-based stable multisplit.
// ---------------------------------------------------------------------------

typedef __attribute__((ext_vector_type(4))) float          f32x4;
typedef __attribute__((ext_vector_type(4))) unsigned short u16x4;
typedef __attribute__((ext_vector_type(8))) unsigned short u16x8;

__device__ __forceinline__ float bf2f(unsigned short u) {
    unsigned int x = ((unsigned int)u) << 16;
    return __builtin_bit_cast(float, x);
}
__device__ __forceinline__ unsigned short f2bf(float f) {
    unsigned int x = __builtin_bit_cast(unsigned int, f);
    x += 0x7FFFu + ((x >> 16) & 1u);
    return (unsigned short)(x >> 16);
}

// ---------------------------------------------------------------------------
// Kernel 1a: qk projection. fp32, sequential ascending-k FMA. [B,H,S,D] fp32.
// ---------------------------------------------------------------------------
__global__ __launch_bounds__(256)
void gemm_qk(const float* __restrict__ hidden,
             const float* __restrict__ wqk,
             float* __restrict__ qk_out)
{
    __shared__ float As[16][132];
    __shared__ float Bs[16][68];
    const int tid = threadIdx.x;
    const int bm  = blockIdx.x;     // 0..63
    const int bn  = blockIdx.y;     // 0..15

    const float* Asrc = hidden + (size_t)bm * 128 * 1024;
    const float* Bsrc = wqk + (size_t)bn * 64 * 1024;

    const int mt = (tid & 15) * 8;
    const int nt = (tid >> 4) * 4;

    float acc[8][4];
#pragma unroll
    for (int r = 0; r < 8; ++r)
#pragma unroll
        for (int c = 0; c < 4; ++c) acc[r][c] = 0.f;

    int arow[2], akof[2];
#pragma unroll
    for (int i = 0; i < 2; ++i) {
        const int c = i * 256 + tid;
        arow[i] = c >> 2;
        akof[i] = (c & 3) * 4;
    }
    const int brow = tid >> 2;
    const int bkof = (tid & 3) * 4;

    f32x4 apre[2], bpre;
#pragma unroll
    for (int i = 0; i < 2; ++i)
        apre[i] = *(const f32x4*)(Asrc + (size_t)arow[i] * 1024 + akof[i]);
    bpre = *(const f32x4*)(Bsrc + (size_t)brow * 1024 + bkof);

    for (int ks = 0; ks < 64; ++ks) {     // K = 64 tiles * 16, ascending
#pragma unroll
        for (int i = 0; i < 2; ++i)
#pragma unroll
            for (int j = 0; j < 4; ++j)
                As[akof[i] + j][arow[i]] = apre[i][j];
#pragma unroll
        for (int j = 0; j < 4; ++j)
            Bs[bkof + j][brow] = bpre[j];
        __syncthreads();
        if (ks < 63) {
            const int k0 = (ks + 1) * 16;
#pragma unroll
            for (int i = 0; i < 2; ++i)
                apre[i] = *(const f32x4*)(Asrc + (size_t)arow[i] * 1024 + k0 + akof[i]);
            bpre = *(const f32x4*)(Bsrc + (size_t)brow * 1024 + k0 + bkof);
        }
#pragma unroll
        for (int k = 0; k < 16; ++k) {
            f32x4 a0 = *(const f32x4*)&As[k][mt];
            f32x4 a1 = *(const f32x4*)&As[k][mt + 4];
            f32x4 b  = *(const f32x4*)&Bs[k][nt];
#pragma unroll
            for (int c = 0; c < 4; ++c) {
                acc[0][c] = __builtin_fmaf(a0[0], b[c], acc[0][c]);
                acc[1][c] = __builtin_fmaf(a0[1], b[c], acc[1][c]);
                acc[2][c] = __builtin_fmaf(a0[2], b[c], acc[2][c]);
                acc[3][c] = __builtin_fmaf(a0[3], b[c], acc[3][c]);
                acc[4][c] = __builtin_fmaf(a1[0], b[c], acc[4][c]);
                acc[5][c] = __builtin_fmaf(a1[1], b[c], acc[5][c]);
                acc[6][c] = __builtin_fmaf(a1[2], b[c], acc[6][c]);
                acc[7][c] = __builtin_fmaf(a1[3], b[c], acc[7][c]);
            }
        }
        __syncthreads();
    }

#pragma unroll
    for (int r = 0; r < 8; ++r) {
        const int m  = bm * 128 + mt + r;
        const int bb = m >> 12, s = m & 4095;
#pragma unroll
        for (int c = 0; c < 4; ++c) {
            const int n  = bn * 64 + nt + c;
            const int hh = n >> 6, d = n & 63;
            qk_out[(((size_t)(bb * 16 + hh)) * 4096 + s) * 64 + d] = acc[r][c];
        }
    }
}

// ---------------------------------------------------------------------------
// Kernel 1b: v projection, fp32 sequential FMA -> bf16 [B,H,S,D].
// ---------------------------------------------------------------------------
__global__ __launch_bounds__(256)
void gemm_v(const float* __restrict__ hidden,
            const float* __restrict__ wv,
            unsigned short* __restrict__ v_out)
{
    __shared__ float As[16][132];
    __shared__ float Bs[16][68];
    const int tid = threadIdx.x;
    const int bm  = blockIdx.x;
    const int bn  = blockIdx.y;

    const float* Asrc = hidden + (size_t)bm * 128 * 1024;
    const float* Bsrc = wv + (size_t)bn * 64 * 1024;

    const int mt = (tid & 15) * 8;
    const int nt = (tid >> 4) * 4;

    float acc[8][4];
#pragma unroll
    for (int r = 0; r < 8; ++r)
#pragma unroll
        for (int c = 0; c < 4; ++c) acc[r][c] = 0.f;

    int arow[2], akof[2];
#pragma unroll
    for (int i = 0; i < 2; ++i) {
        const int c = i * 256 + tid;
        arow[i] = c >> 2;
        akof[i] = (c & 3) * 4;
    }
    const int brow = tid >> 2;
    const int bkof = (tid & 3) * 4;

    f32x4 apre[2], bpre;
#pragma unroll
    for (int i = 0; i < 2; ++i)
        apre[i] = *(const f32x4*)(Asrc + (size_t)arow[i] * 1024 + akof[i]);
    bpre = *(const f32x4*)(Bsrc + (size_t)brow * 1024 + bkof);

    for (int ks = 0; ks < 64; ++ks) {
#pragma unroll
        for (int i = 0; i < 2; ++i)
#pragma unroll
            for (int j = 0; j < 4; ++j)
                As[akof[i] + j][arow[i]] = apre[i][j];
#pragma unroll
        for (int j = 0; j < 4; ++j)
            Bs[bkof + j][brow] = bpre[j];
        __syncthreads();
        if (ks < 63) {
            const int k0 = (ks + 1) * 16;
#pragma unroll
            for (int i = 0; i < 2; ++i)
                apre[i] = *(const f32x4*)(Asrc + (size_t)arow[i] * 1024 + k0 + akof[i]);
            bpre = *(const f32x4*)(Bsrc + (size_t)brow * 1024 + k0 + bkof);
        }
#pragma unroll
        for (int k = 0; k < 16; ++k) {
            f32x4 a0 = *(const f32x4*)&As[k][mt];
            f32x4 a1 = *(const f32x4*)&As[k][mt + 4];
            f32x4 b  = *(const f32x4*)&Bs[k][nt];
#pragma unroll
            for (int c = 0; c < 4; ++c) {
                acc[0][c] = __builtin_fmaf(a0[0], b[c], acc[0][c]);
                acc[1][c] = __builtin_fmaf(a0[1], b[c], acc[1][c]);
                acc[2][c] = __builtin_fmaf(a0[2], b[c], acc[2][c]);
                acc[3][c] = __builtin_fmaf(a0[3], b[c], acc[3][c]);
                acc[4][c] = __builtin_fmaf(a1[0], b[c], acc[4][c]);
                acc[5][c] = __builtin_fmaf(a1[1], b[c], acc[5][c]);
                acc[6][c] = __builtin_fmaf(a1[2], b[c], acc[6][c]);
                acc[7][c] = __builtin_fmaf(a1[3], b[c], acc[7][c]);
            }
        }
        __syncthreads();
    }

#pragma unroll
    for (int r = 0; r < 8; ++r) {
        const int m  = bm * 128 + mt + r;
        const int bb = m >> 12, s = m & 4095;
#pragma unroll
        for (int c = 0; c < 4; ++c) {
            const int n  = bn * 64 + nt + c;
            const int hh = n >> 6, d = n & 63;
            v_out[(((size_t)(bb * 16 + hh)) * 4096 + s) * 64 + d] = f2bf(acc[r][c]);
        }
    }
}

// ---------------------------------------------------------------------------
// Kernel 2: hashing. Sequential ascending-d fp32 FMA; argmax over
// concat(rot,-rot), first-occurrence ties. One wave per row-group.
// ---------------------------------------------------------------------------
__global__ __launch_bounds__(256)
void hash_kernel(const float* __restrict__ qk,
                 const float* __restrict__ rotf,
                 int* __restrict__ buckets)
{
    __shared__ float rot[8192];       // [d][n*64+r]
    __shared__ float rows[64 * 64];
    const int tid = threadIdx.x;
    for (int i = tid; i < 8192; i += 256) rot[i] = rotf[i];
    const int rbase = blockIdx.x * 64;
    {
        const f32x4* src = (const f32x4*)(qk + (size_t)rbase * 64);
        f32x4* dst = (f32x4*)rows;
#pragma unroll
        for (int i = 0; i < 4; ++i) dst[tid + i * 256] = src[tid + i * 256];
    }
    __syncthreads();
    const int w = tid >> 6, lane = tid & 63;
    for (int rr = 0; rr < 16; ++rr) {
        const int row = w * 16 + rr;
        float a0 = 0.f, a1 = 0.f;
#pragma unroll
        for (int dg = 0; dg < 16; ++dg) {
            f32x4 qb = *(const f32x4*)&rows[row * 64 + dg * 4];
#pragma unroll
            for (int j = 0; j < 4; ++j) {
                const int d = dg * 4 + j;
                a0 = __builtin_fmaf(qb[j], rot[d * 128 + lane],      a0);
                a1 = __builtin_fmaf(qb[j], rot[d * 128 + 64 + lane], a1);
            }
        }
        float v0, v1; int i0, i1;
        if (a0 >= -a0) { v0 = a0;  i0 = lane; } else { v0 = -a0; i0 = 64 + lane; }
        if (a1 >= -a1) { v1 = a1;  i1 = lane; } else { v1 = -a1; i1 = 64 + lane; }
#pragma unroll
        for (int m = 1; m < 64; m <<= 1) {
            float ov = __shfl_xor(v0, m); int oi = __shfl_xor(i0, m);
            if (ov > v0 || (ov == v0 && oi < i0)) { v0 = ov; i0 = oi; }
            ov = __shfl_xor(v1, m); oi = __shfl_xor(i1, m);
            if (ov > v1 || (ov == v1 && oi < i1)) { v1 = ov; i1 = oi; }
        }
        if (lane == 0) {
            const int g = rbase + row;
            const int bh = g >> 12, s = g & 4095;
            buckets[(size_t)bh * 8192 + s]        = i0;          // hash 0
            buckets[(size_t)bh * 8192 + 4096 + s] = i1 + 128;    // hash 1
        }
    }
}

// ---------------------------------------------------------------------------
// Kernel 3: stable counting sort per (b,h) by (bucket, position).
// Ballot-based multisplit: histogram + prefix, then 32 chunks of 256 items;
// within-chunk stable rank via 8-bit ballot matching + per-wave histograms.
// ---------------------------------------------------------------------------
__global__ __launch_bounds__(256)
void sort_kernel(const int* __restrict__ buckets, int* __restrict__ sorted)
{
    __shared__ unsigned char  lb[8192];
    __shared__ unsigned short sl[8192];
    __shared__ int cnt[256];
    __shared__ int base[256];
    __shared__ unsigned short whist[4][256];
    const int tid  = threadIdx.x;
    const int bh   = blockIdx.x;
    const int lane = tid & 63;
    const int w    = tid >> 6;

    cnt[tid] = 0;
    for (int i = tid; i < 8192; i += 256)
        lb[i] = (unsigned char)buckets[(size_t)bh * 8192 + i];
    __syncthreads();
    for (int i = tid; i < 8192; i += 256) atomicAdd(&cnt[lb[i]], 1);
    __syncthreads();

    // exclusive prefix sum over cnt -> base (Hillis-Steele inclusive, shift)
    base[tid] = cnt[tid];
    __syncthreads();
#pragma unroll
    for (int off = 1; off < 256; off <<= 1) {
        int t = (tid >= off) ? base[tid - off] : 0;
        __syncthreads();
        base[tid] += t;
        __syncthreads();
    }
    {
        int ex = base[tid] - cnt[tid];
        __syncthreads();
        base[tid] = ex;
        __syncthreads();
    }

    for (int c = 0; c < 32; ++c) {
        const int i = c * 256 + tid;
        const int b = lb[i];
        // zero per-wave histograms
        whist[0][tid] = 0; whist[1][tid] = 0; whist[2][tid] = 0; whist[3][tid] = 0;
        __syncthreads();
        // 64-lane group mask of lanes with same bucket (8-bit match)
        unsigned long long m = ~0ull;
#pragma unroll
        for (int bit = 0; bit < 8; ++bit) {
            const unsigned long long bb = __ballot((b >> bit) & 1);
            m &= ((b >> bit) & 1) ? bb : ~bb;
        }
        const unsigned long long ltmask = (lane == 63) ? ~0ull >> 1
                                         : ((1ull << lane) - 1);
        const int rank_in_wave = __popcll(m & ltmask);
        if (rank_in_wave == 0)
            whist[w][b] = (unsigned short)__popcll(m);
        __syncthreads();
        int rank = rank_in_wave;
#pragma unroll
        for (int ww = 0; ww < 3; ++ww)
            if (ww < w) rank += whist[ww][b];
        const int pos = base[b] + rank;
        sl[pos] = (unsigned short)i;
        __syncthreads();
        base[tid] += whist[0][tid] + whist[1][tid] + whist[2][tid] + whist[3][tid];
        __syncthreads();
    }

    for (int i = tid; i < 8192; i += 256)
        sorted[(size_t)bh * 8192 + i] = (int)sl[i];
}

// ---------------------------------------------------------------------------
// Kernel 4: fused chunked attention. One block per (b,h,chunk): dots ->
// logsumexp -> probs -> PV in one pass. Writes per-hash out (bf16, plain
// scattered 256B stores, NO atomics) + logits.
// ---------------------------------------------------------------------------
__global__ __launch_bounds__(256)
void attn_kernel(const float* __restrict__ qk,
                 const unsigned short* __restrict__ vb,
                 const int* __restrict__ sorted,
                 unsigned short* __restrict__ out_hash,
                 float* __restrict__ logits)
{
    __shared__ float          kk[128 * 68];
    __shared__ unsigned short vv[128 * 64];
    __shared__ float scl[128];
    __shared__ int   stick[128];
    __shared__ int   qtick[64];
    __shared__ float red[512];
    const int tid = threadIdx.x;
    const int c  = blockIdx.x;
    const int bh = blockIdx.z * 16 + blockIdx.y;
    const int pc = (c + 127) & 127;

    if (tid < 128) {
        const int p  = (tid < 64) ? (pc * 64 + tid) : (c * 64 + (tid - 64));
        const int tk = sorted[(size_t)bh * 8192 + p];
        stick[tid] = tk & 4095;
        if (tid >= 64) qtick[tid - 64] = tk;
    }
    __syncthreads();
    {
        const int r = tid >> 1, half = tid & 1;
        const int srow = stick[r];
        const f32x4* src = (const f32x4*)(qk + (((size_t)bh * 4096 + srow) << 6) + half * 32);
#pragma unroll
        for (int i = 0; i < 8; ++i)
            *(f32x4*)&kk[r * 68 + half * 32 + i * 4] = src[i];
        const unsigned short* vs = vb + (((size_t)bh * 4096 + srow) << 6) + half * 32;
#pragma unroll
        for (int i = 0; i < 4; ++i)
            *(u16x8*)&vv[r * 64 + half * 32 + i * 8] = *(const u16x8*)(vs + i * 8);
    }
    __syncthreads();
    if (tid < 128) {
        float ss = 0.f;
#pragma unroll
        for (int dg = 0; dg < 16; ++dg) {
            f32x4 x = *(const f32x4*)&kk[tid * 68 + dg * 4];
            ss += x[0]*x[0] + x[1]*x[1] + x[2]*x[2] + x[3]*x[3];
        }
        scl[tid] = (1.0f / sqrtf(ss * (1.0f / 64.0f) + 1e-6f)) * 0.125f;
    }
    __syncthreads();

    const int q = tid & 63, kb = tid >> 6;
    float qreg[64];
#pragma unroll
    for (int dg = 0; dg < 16; ++dg) {
        f32x4 x = *(const f32x4*)&kk[(64 + q) * 68 + dg * 4];
        qreg[dg*4+0] = x[0]; qreg[dg*4+1] = x[1]; qreg[dg*4+2] = x[2]; qreg[dg*4+3] = x[3];
    }
    const int tq = stick[64 + q];

    float dots[32];
#pragma unroll
    for (int j = 0; j < 32; ++j) {
        const int k = kb * 32 + j;
        float a = 0.f;
#pragma unroll
        for (int dg = 0; dg < 16; ++dg) {
            f32x4 kv = *(const f32x4*)&kk[k * 68 + dg * 4];
            a += qreg[dg*4+0]*kv[0] + qreg[dg*4+1]*kv[1]
               + qreg[dg*4+2]*kv[2] + qreg[dg*4+3]*kv[3];
        }
        a *= scl[k];
        const int tk = stick[k];
        if (tq < tk)  a = -1e9f;
        if (tq == tk) a = -1e5f;
        dots[j] = a;
    }

    float mloc = -3.4e38f;
#pragma unroll
    for (int j = 0; j < 32; ++j) mloc = fmaxf(mloc, dots[j]);
    red[kb * 64 + q] = mloc;
    __syncthreads();
    const float M = fmaxf(fmaxf(red[q], red[64 + q]), fmaxf(red[128 + q], red[192 + q]));
    float l = 0.f;
#pragma unroll
    for (int j = 0; j < 32; ++j) l += expf(dots[j] - M);
    red[256 + kb * 64 + q] = l;
    __syncthreads();
    const float L = red[256 + q] + red[320 + q] + red[384 + q] + red[448 + q];
    const float logit = M + logf(L);
#pragma unroll
    for (int j = 0; j < 32; ++j) dots[j] = expf(dots[j] - logit);   // probs

    float o[64];
#pragma unroll
    for (int i = 0; i < 64; ++i) o[i] = 0.f;
#pragma unroll
    for (int j = 0; j < 32; ++j) {
        const float p = dots[j];
        const int k = kb * 32 + j;
#pragma unroll
        for (int dg = 0; dg < 8; ++dg) {
            u16x8 vx = *(const u16x8*)&vv[k * 64 + dg * 8];
#pragma unroll
            for (int e = 0; e < 8; ++e) o[dg * 8 + e] += p * bf2f(vx[e]);
        }
    }
    __syncthreads();                 // all kk reads complete; reuse as outbuf
    float* outb = kk;                // pitch 68
#pragma unroll
    for (int rs = 0; rs < 4; ++rs) {
        if (kb == rs) {
#pragma unroll
            for (int dg = 0; dg < 16; ++dg) {
                f32x4 val = {o[dg*4+0], o[dg*4+1], o[dg*4+2], o[dg*4+3]};
                f32x4* dst = (f32x4*)&outb[q * 68 + dg * 4];
                if (rs == 0) *dst = val;
                else { f32x4 old = *dst; *dst = old + val; }
            }
        }
        __syncthreads();
    }

    if (tid < 64) {   // logit identical across kb for same q
        const int tk = qtick[tid];
        logits[((size_t)bh * 2 + (tk >> 12)) * 4096 + (tk & 4095)] = logit;
    }
    {
        const int qq = tid >> 2, part = tid & 3;
        const int tk = qtick[qq];
        const size_t ob = (((size_t)bh * 2 + (tk >> 12)) * 4096 + (tk & 4095)) * 64 + part * 16;
#pragma unroll
        for (int i = 0; i < 16; i += 4) {
            u16x4 uu;
            uu[0] = f2bf(outb[qq * 68 + part * 16 + i + 0]);
            uu[1] = f2bf(outb[qq * 68 + part * 16 + i + 1]);
            uu[2] = f2bf(outb[qq * 68 + part * 16 + i + 2]);
            uu[3] = f2bf(outb[qq * 68 + part * 16 + i + 3]);
            *(u16x4*)(out_hash + ob + i) = uu;
        }
    }
}

// ---------------------------------------------------------------------------
// Kernel 5: combine hash rounds with logsumexp weights; emit fp32 [B,S,H*D].
// ---------------------------------------------------------------------------
__global__ __launch_bounds__(256)
void combine_kernel(const unsigned short* __restrict__ out_hash,
                    const float* __restrict__ logits,
                    float* __restrict__ out)
{
    const int idx  = blockIdx.x * 256 + threadIdx.x;   // < 2097152
    const int bh   = idx >> 16;
    const int rem  = idx & 65535;
    const int s    = rem >> 4;
    const int part = rem & 15;
    const float lg0 = logits[((size_t)bh * 2 + 0) * 4096 + s];
    const float lg1 = logits[((size_t)bh * 2 + 1) * 4096 + s];
    const float m  = fmaxf(lg0, lg1);
    const float e0 = expf(lg0 - m), e1 = expf(lg1 - m);
    const float inv = 1.0f / (e0 + e1);
    const float w0 = e0 * inv, w1 = e1 * inv;
    const size_t b0 = (((size_t)bh * 2 + 0) * 4096 + s) * 64 + part * 4;
    const size_t b1 = (((size_t)bh * 2 + 1) * 4096 + s) * 64 + part * 4;
    u16x4 u0 = *(const u16x4*)(out_hash + b0);
    u16x4 u1 = *(const u16x4*)(out_hash + b1);
    const int b = bh >> 4, hh = bh & 15;
    const size_t ob = ((size_t)b * 4096 + s) * 1024 + hh * 64 + part * 4;
    f32x4 r;
#pragma unroll
    for (int e = 0; e < 4; ++e)
        r[e] = w0 * bf2f(u0[e]) + w1 * bf2f(u1[e]);
    *(f32x4*)(out + ob) = r;
}

// ---------------------------------------------------------------------------
extern "C" void kernel_launch(void* const* d_in, const int* in_sizes, int n_in,
                              void* d_out, int out_size, void* d_ws, size_t ws_size,
                              hipStream_t stream) {
    const float* hidden = (const float*)d_in[0];   // [2,4096,1024] fp32
    const float* wqk    = (const float*)d_in[1];   // [1024,1024]   fp32
    const float* wv     = (const float*)d_in[2];   // [1024,1024]   fp32
    const float* rotf   = (const float*)d_in[3];   // [64,2,64]     fp32
    float* out = (float*)d_out;                    // [2,4096,1024] fp32

    char* ws = (char*)d_ws;
    float*          qk       = (float*)(ws);                       // 33,554,432 B
    unsigned short* vb       = (unsigned short*)(ws + 33554432);   // 16,777,216 B
    int*            buckets  = (int*)(ws + 50331648);              //  1,048,576 B
    int*            sorted   = (int*)(ws + 51380224);              //  1,048,576 B
    float*          logits   = (float*)(ws + 52428800);            //  1,048,576 B
    unsigned short* out_hash = (unsigned short*)(ws + 53477376);   // 33,554,432 B
    // total 87,031,808 B

    hipLaunchKernelGGL(gemm_qk,     dim3(64, 16),     dim3(256), 0, stream,
                       hidden, wqk, qk);
    hipLaunchKernelGGL(gemm_v,      dim3(64, 16),     dim3(256), 0, stream,
                       hidden, wv, vb);
    hipLaunchKernelGGL(hash_kernel, dim3(2048),       dim3(256), 0, stream,
                       qk, rotf, buckets);
    hipLaunchKernelGGL(sort_kernel, dim3(32),         dim3(256), 0, stream,
                       buckets, sorted);
    hipLaunchKernelGGL(attn_kernel, dim3(128, 16, 2), dim3(256), 0, stream,
                       qk, vb, sorted, out_hash, logits);
    hipLaunchKernelGGL(combine_kernel, dim3(8192),    dim3(256), 0, stream,
                       out_hash, logits, out);
}

// Round 9
// 686.004 us; speedup vs baseline: 3.4392x; 1.5087x over previous
//
#include <hip/hip_runtime.h>

// ---------------------------------------------------------------------------
// LSH self-attention (Reformer). B=2,S=4096,H=16,D=64,NH=2,NB=128,CHUNK=64,
// N_BEFORE=1. Inputs fp32, output fp32.
// Precision-critical path (qk projection + rotated einsum feeding argmax) is
// fp32 with sequential ascending-k FMA chains (matches np/BLAS order; verified
// PASS rounds 6-8, absmax 0.015625). Attention rewritten on bf16 MFMA
// (smooth path only; buckets unaffected). Sort: ballot stable multisplit.
// ---------------------------------------------------------------------------

typedef __attribute__((ext_vector_type(4))) float          f32x4;
typedef __attribute__((ext_vector_type(4))) unsigned short u16x4;
typedef __attribute__((ext_vector_type(8))) unsigned short u16x8;
typedef __attribute__((ext_vector_type(8))) __bf16         bf16x8;

__device__ __forceinline__ float bf2f(unsigned short u) {
    unsigned int x = ((unsigned int)u) << 16;
    return __builtin_bit_cast(float, x);
}
__device__ __forceinline__ unsigned short f2bf(float f) {
    unsigned int x = __builtin_bit_cast(unsigned int, f);
    x += 0x7FFFu + ((x >> 16) & 1u);
    return (unsigned short)(x >> 16);
}

// ---------------------------------------------------------------------------
// Kernel 1a: qk projection. fp32, sequential ascending-k FMA. [B,H,S,D] fp32.
// ---------------------------------------------------------------------------
__global__ __launch_bounds__(256)
void gemm_qk(const float* __restrict__ hidden,
             const float* __restrict__ wqk,
             float* __restrict__ qk_out)
{
    __shared__ float As[16][132];
    __shared__ float Bs[16][68];
    const int tid = threadIdx.x;
    const int bm  = blockIdx.x;     // 0..63
    const int bn  = blockIdx.y;     // 0..15

    const float* Asrc = hidden + (size_t)bm * 128 * 1024;
    const float* Bsrc = wqk + (size_t)bn * 64 * 1024;

    const int mt = (tid & 15) * 8;
    const int nt = (tid >> 4) * 4;

    float acc[8][4];
#pragma unroll
    for (int r = 0; r < 8; ++r)
#pragma unroll
        for (int c = 0; c < 4; ++c) acc[r][c] = 0.f;

    int arow[2], akof[2];
#pragma unroll
    for (int i = 0; i < 2; ++i) {
        const int c = i * 256 + tid;
        arow[i] = c >> 2;
        akof[i] = (c & 3) * 4;
    }
    const int brow = tid >> 2;
    const int bkof = (tid & 3) * 4;

    f32x4 apre[2], bpre;
#pragma unroll
    for (int i = 0; i < 2; ++i)
        apre[i] = *(const f32x4*)(Asrc + (size_t)arow[i] * 1024 + akof[i]);
    bpre = *(const f32x4*)(Bsrc + (size_t)brow * 1024 + bkof);

    for (int ks = 0; ks < 64; ++ks) {     // K = 64 tiles * 16, ascending
#pragma unroll
        for (int i = 0; i < 2; ++i)
#pragma unroll
            for (int j = 0; j < 4; ++j)
                As[akof[i] + j][arow[i]] = apre[i][j];
#pragma unroll
        for (int j = 0; j < 4; ++j)
            Bs[bkof + j][brow] = bpre[j];
        __syncthreads();
        if (ks < 63) {
            const int k0 = (ks + 1) * 16;
#pragma unroll
            for (int i = 0; i < 2; ++i)
                apre[i] = *(const f32x4*)(Asrc + (size_t)arow[i] * 1024 + k0 + akof[i]);
            bpre = *(const f32x4*)(Bsrc + (size_t)brow * 1024 + k0 + bkof);
        }
#pragma unroll
        for (int k = 0; k < 16; ++k) {
            f32x4 a0 = *(const f32x4*)&As[k][mt];
            f32x4 a1 = *(const f32x4*)&As[k][mt + 4];
            f32x4 b  = *(const f32x4*)&Bs[k][nt];
#pragma unroll
            for (int c = 0; c < 4; ++c) {
                acc[0][c] = __builtin_fmaf(a0[0], b[c], acc[0][c]);
                acc[1][c] = __builtin_fmaf(a0[1], b[c], acc[1][c]);
                acc[2][c] = __builtin_fmaf(a0[2], b[c], acc[2][c]);
                acc[3][c] = __builtin_fmaf(a0[3], b[c], acc[3][c]);
                acc[4][c] = __builtin_fmaf(a1[0], b[c], acc[4][c]);
                acc[5][c] = __builtin_fmaf(a1[1], b[c], acc[5][c]);
                acc[6][c] = __builtin_fmaf(a1[2], b[c], acc[6][c]);
                acc[7][c] = __builtin_fmaf(a1[3], b[c], acc[7][c]);
            }
        }
        __syncthreads();
    }

#pragma unroll
    for (int r = 0; r < 8; ++r) {
        const int m  = bm * 128 + mt + r;
        const int bb = m >> 12, s = m & 4095;
#pragma unroll
        for (int c = 0; c < 4; ++c) {
            const int n  = bn * 64 + nt + c;
            const int hh = n >> 6, d = n & 63;
            qk_out[(((size_t)(bb * 16 + hh)) * 4096 + s) * 64 + d] = acc[r][c];
        }
    }
}

// ---------------------------------------------------------------------------
// Kernel 1b: v projection, fp32 sequential FMA -> bf16 [B,H,S,D].
// ---------------------------------------------------------------------------
__global__ __launch_bounds__(256)
void gemm_v(const float* __restrict__ hidden,
            const float* __restrict__ wv,
            unsigned short* __restrict__ v_out)
{
    __shared__ float As[16][132];
    __shared__ float Bs[16][68];
    const int tid = threadIdx.x;
    const int bm  = blockIdx.x;
    const int bn  = blockIdx.y;

    const float* Asrc = hidden + (size_t)bm * 128 * 1024;
    const float* Bsrc = wv + (size_t)bn * 64 * 1024;

    const int mt = (tid & 15) * 8;
    const int nt = (tid >> 4) * 4;

    float acc[8][4];
#pragma unroll
    for (int r = 0; r < 8; ++r)
#pragma unroll
        for (int c = 0; c < 4; ++c) acc[r][c] = 0.f;

    int arow[2], akof[2];
#pragma unroll
    for (int i = 0; i < 2; ++i) {
        const int c = i * 256 + tid;
        arow[i] = c >> 2;
        akof[i] = (c & 3) * 4;
    }
    const int brow = tid >> 2;
    const int bkof = (tid & 3) * 4;

    f32x4 apre[2], bpre;
#pragma unroll
    for (int i = 0; i < 2; ++i)
        apre[i] = *(const f32x4*)(Asrc + (size_t)arow[i] * 1024 + akof[i]);
    bpre = *(const f32x4*)(Bsrc + (size_t)brow * 1024 + bkof);

    for (int ks = 0; ks < 64; ++ks) {
#pragma unroll
        for (int i = 0; i < 2; ++i)
#pragma unroll
            for (int j = 0; j < 4; ++j)
                As[akof[i] + j][arow[i]] = apre[i][j];
#pragma unroll
        for (int j = 0; j < 4; ++j)
            Bs[bkof + j][brow] = bpre[j];
        __syncthreads();
        if (ks < 63) {
            const int k0 = (ks + 1) * 16;
#pragma unroll
            for (int i = 0; i < 2; ++i)
                apre[i] = *(const f32x4*)(Asrc + (size_t)arow[i] * 1024 + k0 + akof[i]);
            bpre = *(const f32x4*)(Bsrc + (size_t)brow * 1024 + k0 + bkof);
        }
#pragma unroll
        for (int k = 0; k < 16; ++k) {
            f32x4 a0 = *(const f32x4*)&As[k][mt];
            f32x4 a1 = *(const f32x4*)&As[k][mt + 4];
            f32x4 b  = *(const f32x4*)&Bs[k][nt];
#pragma unroll
            for (int c = 0; c < 4; ++c) {
                acc[0][c] = __builtin_fmaf(a0[0], b[c], acc[0][c]);
                acc[1][c] = __builtin_fmaf(a0[1], b[c], acc[1][c]);
                acc[2][c] = __builtin_fmaf(a0[2], b[c], acc[2][c]);
                acc[3][c] = __builtin_fmaf(a0[3], b[c], acc[3][c]);
                acc[4][c] = __builtin_fmaf(a1[0], b[c], acc[4][c]);
                acc[5][c] = __builtin_fmaf(a1[1], b[c], acc[5][c]);
                acc[6][c] = __builtin_fmaf(a1[2], b[c], acc[6][c]);
                acc[7][c] = __builtin_fmaf(a1[3], b[c], acc[7][c]);
            }
        }
        __syncthreads();
    }

#pragma unroll
    for (int r = 0; r < 8; ++r) {
        const int m  = bm * 128 + mt + r;
        const int bb = m >> 12, s = m & 4095;
#pragma unroll
        for (int c = 0; c < 4; ++c) {
            const int n  = bn * 64 + nt + c;
            const int hh = n >> 6, d = n & 63;
            v_out[(((size_t)(bb * 16 + hh)) * 4096 + s) * 64 + d] = f2bf(acc[r][c]);
        }
    }
}

// ---------------------------------------------------------------------------
// Kernel 2: hashing. Sequential ascending-d fp32 FMA; argmax over
// concat(rot,-rot), first-occurrence ties. One wave per row-group.
// ---------------------------------------------------------------------------
__global__ __launch_bounds__(256)
void hash_kernel(const float* __restrict__ qk,
                 const float* __restrict__ rotf,
                 int* __restrict__ buckets)
{
    __shared__ float rot[8192];       // [d][n*64+r]
    __shared__ float rows[64 * 64];
    const int tid = threadIdx.x;
    for (int i = tid; i < 8192; i += 256) rot[i] = rotf[i];
    const int rbase = blockIdx.x * 64;
    {
        const f32x4* src = (const f32x4*)(qk + (size_t)rbase * 64);
        f32x4* dst = (f32x4*)rows;
#pragma unroll
        for (int i = 0; i < 4; ++i) dst[tid + i * 256] = src[tid + i * 256];
    }
    __syncthreads();
    const int w = tid >> 6, lane = tid & 63;
    for (int rr = 0; rr < 16; ++rr) {
        const int row = w * 16 + rr;
        float a0 = 0.f, a1 = 0.f;
#pragma unroll
        for (int dg = 0; dg < 16; ++dg) {
            f32x4 qb = *(const f32x4*)&rows[row * 64 + dg * 4];
#pragma unroll
            for (int j = 0; j < 4; ++j) {
                const int d = dg * 4 + j;
                a0 = __builtin_fmaf(qb[j], rot[d * 128 + lane],      a0);
                a1 = __builtin_fmaf(qb[j], rot[d * 128 + 64 + lane], a1);
            }
        }
        float v0, v1; int i0, i1;
        if (a0 >= -a0) { v0 = a0;  i0 = lane; } else { v0 = -a0; i0 = 64 + lane; }
        if (a1 >= -a1) { v1 = a1;  i1 = lane; } else { v1 = -a1; i1 = 64 + lane; }
#pragma unroll
        for (int m = 1; m < 64; m <<= 1) {
            float ov = __shfl_xor(v0, m); int oi = __shfl_xor(i0, m);
            if (ov > v0 || (ov == v0 && oi < i0)) { v0 = ov; i0 = oi; }
            ov = __shfl_xor(v1, m); oi = __shfl_xor(i1, m);
            if (ov > v1 || (ov == v1 && oi < i1)) { v1 = ov; i1 = oi; }
        }
        if (lane == 0) {
            const int g = rbase + row;
            const int bh = g >> 12, s = g & 4095;
            buckets[(size_t)bh * 8192 + s]        = i0;          // hash 0
            buckets[(size_t)bh * 8192 + 4096 + s] = i1 + 128;    // hash 1
        }
    }
}

// ---------------------------------------------------------------------------
// Kernel 3: stable counting sort per (b,h) by (bucket, position).
// Ballot-based multisplit (round-8 verified).
// ---------------------------------------------------------------------------
__global__ __launch_bounds__(256)
void sort_kernel(const int* __restrict__ buckets, int* __restrict__ sorted)
{
    __shared__ unsigned char  lb[8192];
    __shared__ unsigned short sl[8192];
    __shared__ int cnt[256];
    __shared__ int base[256];
    __shared__ unsigned short whist[4][256];
    const int tid  = threadIdx.x;
    const int bh   = blockIdx.x;
    const int lane = tid & 63;
    const int w    = tid >> 6;

    cnt[tid] = 0;
    for (int i = tid; i < 8192; i += 256)
        lb[i] = (unsigned char)buckets[(size_t)bh * 8192 + i];
    __syncthreads();
    for (int i = tid; i < 8192; i += 256) atomicAdd(&cnt[lb[i]], 1);
    __syncthreads();

    base[tid] = cnt[tid];
    __syncthreads();
#pragma unroll
    for (int off = 1; off < 256; off <<= 1) {
        int t = (tid >= off) ? base[tid - off] : 0;
        __syncthreads();
        base[tid] += t;
        __syncthreads();
    }
    {
        int ex = base[tid] - cnt[tid];
        __syncthreads();
        base[tid] = ex;
        __syncthreads();
    }

    for (int c = 0; c < 32; ++c) {
        const int i = c * 256 + tid;
        const int b = lb[i];
        whist[0][tid] = 0; whist[1][tid] = 0; whist[2][tid] = 0; whist[3][tid] = 0;
        __syncthreads();
        unsigned long long m = ~0ull;
#pragma unroll
        for (int bit = 0; bit < 8; ++bit) {
            const unsigned long long bb = __ballot((b >> bit) & 1);
            m &= ((b >> bit) & 1) ? bb : ~bb;
        }
        const unsigned long long ltmask = (lane == 63) ? ~0ull >> 1
                                         : ((1ull << lane) - 1);
        const int rank_in_wave = __popcll(m & ltmask);
        if (rank_in_wave == 0)
            whist[w][b] = (unsigned short)__popcll(m);
        __syncthreads();
        int rank = rank_in_wave;
#pragma unroll
        for (int ww = 0; ww < 3; ++ww)
            if (ww < w) rank += whist[ww][b];
        const int pos = base[b] + rank;
        sl[pos] = (unsigned short)i;
        __syncthreads();
        base[tid] += whist[0][tid] + whist[1][tid] + whist[2][tid] + whist[3][tid];
        __syncthreads();
    }

    for (int i = tid; i < 8192; i += 256)
        sorted[(size_t)bh * 8192 + i] = (int)sl[i];
}

// ---------------------------------------------------------------------------
// Kernel 4: MFMA fused chunked attention. One block per (b,h,chunk).
// QK^T (bf16 MFMA, fp32 acc) -> in-register softmax (16-lane shfl reduce)
// -> P via LDS (C-layout -> A-layout) -> PV (bf16 MFMA) -> bf16 scatter.
// Layouts [m89/m118-verified]: C/D col=lane&15,row=quad*4+reg;
// A/B row=lane&15, k=quad*8+j.
// ---------------------------------------------------------------------------
#define KQP 72    // kq pitch (shorts): 144B rows, 16B-aligned, 2-way banks
#define VPP 136   // vvt/Pm pitch (shorts): 272B rows, 16B-aligned, 2-way banks

__global__ __launch_bounds__(256)
void attn_kernel(const float* __restrict__ qk,
                 const unsigned short* __restrict__ vb,
                 const int* __restrict__ sorted,
                 unsigned short* __restrict__ out_hash,
                 float* __restrict__ logits)
{
    __shared__ unsigned short kq[128 * KQP];   // bf16 qk rows (keys 0-127; queries = rows 64-127)
    __shared__ unsigned short vvt[64 * VPP];   // bf16 v transposed [d][key]
    __shared__ unsigned short Pm[64 * VPP];    // bf16 probs [q][key]
    __shared__ float scl[128];
    __shared__ unsigned short stick[128];
    __shared__ unsigned short qtick_lo[64];    // tk & 4095
    __shared__ unsigned short qtick_hi[64];    // tk >> 12
    __shared__ float lg[64];
    float* ssqf = (float*)Pm;                  // staging scratch (256 floats)

    const int tid = threadIdx.x;
    const int c  = blockIdx.x;
    const int bh = blockIdx.z * 16 + blockIdx.y;
    const int pc = (c + 127) & 127;

    if (tid < 128) {
        const int p  = (tid < 64) ? (pc * 64 + tid) : (c * 64 + (tid - 64));
        const int tk = sorted[(size_t)bh * 8192 + p];
        stick[tid] = (unsigned short)(tk & 4095);
        if (tid >= 64) {
            qtick_lo[tid - 64] = (unsigned short)(tk & 4095);
            qtick_hi[tid - 64] = (unsigned short)(tk >> 12);
        }
    }
    __syncthreads();

    // ---- staging: qk rows -> bf16 kq (+sumsq partials), v rows -> vvt^T ----
    {
        const int r = tid >> 1, half = tid & 1;
        const int srow = stick[r];
        const f32x4* src = (const f32x4*)(qk + (((size_t)bh * 4096 + srow) << 6) + half * 32);
        float ss = 0.f;
#pragma unroll
        for (int i = 0; i < 8; ++i) {
            f32x4 x = src[i];
            ss += x[0]*x[0] + x[1]*x[1] + x[2]*x[2] + x[3]*x[3];
            u16x4 uu;
            uu[0] = f2bf(x[0]); uu[1] = f2bf(x[1]);
            uu[2] = f2bf(x[2]); uu[3] = f2bf(x[3]);
            *(u16x4*)&kq[r * KQP + half * 32 + i * 4] = uu;
        }
        ssqf[r * 2 + half] = ss;

        const unsigned short* vs = vb + (((size_t)bh * 4096 + srow) << 6) + half * 32;
        unsigned short vtmp[32];
#pragma unroll
        for (int i = 0; i < 4; ++i)
            *(u16x8*)&vtmp[i * 8] = *(const u16x8*)(vs + i * 8);
#pragma unroll
        for (int j = 0; j < 32; ++j)
            vvt[(half * 32 + j) * VPP + r] = vtmp[j];
    }
    __syncthreads();
    if (tid < 128) {
        const float ss = ssqf[tid * 2] + ssqf[tid * 2 + 1];
        scl[tid] = (1.0f / sqrtf(ss * (1.0f / 64.0f) + 1e-6f)) * 0.125f;
    }
    __syncthreads();

    const int w    = tid >> 6;          // wave -> q-strip [w*16, w*16+16)
    const int lane = tid & 63;
    const int l16  = lane & 15;
    const int quad = lane >> 4;

    // ---- QK^T: 16 MFMA per wave ----
    f32x4 accS[8];
#pragma unroll
    for (int t = 0; t < 8; ++t) accS[t] = f32x4{0.f, 0.f, 0.f, 0.f};
#pragma unroll
    for (int kst = 0; kst < 2; ++kst) {
        const bf16x8 aq = *(const bf16x8*)&kq[(64 + w * 16 + l16) * KQP + kst * 32 + quad * 8];
#pragma unroll
        for (int t = 0; t < 8; ++t) {
            const bf16x8 bk = *(const bf16x8*)&kq[(t * 16 + l16) * KQP + kst * 32 + quad * 8];
            accS[t] = __builtin_amdgcn_mfma_f32_16x16x32_bf16(aq, bk, accS[t], 0, 0, 0);
        }
    }

    // ---- scale + mask + softmax (in-register, 16-lane reduce) ----
    float sct[8]; int tkt[8];
#pragma unroll
    for (int t = 0; t < 8; ++t) {
        sct[t] = scl[t * 16 + l16];
        tkt[t] = (int)stick[t * 16 + l16];
    }
    int tqr[4];
#pragma unroll
    for (int r = 0; r < 4; ++r) tqr[r] = (int)stick[64 + w * 16 + quad * 4 + r];

    float val[8][4];
#pragma unroll
    for (int t = 0; t < 8; ++t)
#pragma unroll
        for (int r = 0; r < 4; ++r) {
            float a = accS[t][r] * sct[t];
            if (tqr[r] <  tkt[t]) a = -1e9f;
            if (tqr[r] == tkt[t]) a = -1e5f;
            val[t][r] = a;
        }

    float inv_r[4], logit_r[4];
#pragma unroll
    for (int r = 0; r < 4; ++r) {
        float m = val[0][r];
#pragma unroll
        for (int t = 1; t < 8; ++t) m = fmaxf(m, val[t][r]);
        m = fmaxf(m, __shfl_xor(m, 1));
        m = fmaxf(m, __shfl_xor(m, 2));
        m = fmaxf(m, __shfl_xor(m, 4));
        m = fmaxf(m, __shfl_xor(m, 8));
        float l = 0.f;
#pragma unroll
        for (int t = 0; t < 8; ++t) { val[t][r] = expf(val[t][r] - m); l += val[t][r]; }
        l += __shfl_xor(l, 1);
        l += __shfl_xor(l, 2);
        l += __shfl_xor(l, 4);
        l += __shfl_xor(l, 8);
        logit_r[r] = m + logf(l);
        inv_r[r]   = 1.0f / l;
    }

    // P (bf16) to LDS in [q][key] layout; logits to LDS
#pragma unroll
    for (int t = 0; t < 8; ++t)
#pragma unroll
        for (int r = 0; r < 4; ++r)
            Pm[(w * 16 + quad * 4 + r) * VPP + t * 16 + l16] = f2bf(val[t][r] * inv_r[r]);
    if (l16 == 0) {
#pragma unroll
        for (int r = 0; r < 4; ++r) lg[w * 16 + quad * 4 + r] = logit_r[r];
    }
    __syncthreads();

    // ---- PV: 16 MFMA per wave ----
    f32x4 accO[4];
#pragma unroll
    for (int dt = 0; dt < 4; ++dt) accO[dt] = f32x4{0.f, 0.f, 0.f, 0.f};
#pragma unroll
    for (int kst = 0; kst < 4; ++kst) {
        const bf16x8 ap = *(const bf16x8*)&Pm[(w * 16 + l16) * VPP + kst * 32 + quad * 8];
#pragma unroll
        for (int dt = 0; dt < 4; ++dt) {
            const bf16x8 bv = *(const bf16x8*)&vvt[(dt * 16 + l16) * VPP + kst * 32 + quad * 8];
            accO[dt] = __builtin_amdgcn_mfma_f32_16x16x32_bf16(ap, bv, accO[dt], 0, 0, 0);
        }
    }

    // ---- output: bf16 via LDS (reuse kq as outb [64][KQP]) ----
    unsigned short* outb = kq;   // all kq reads completed before Pm barrier
#pragma unroll
    for (int dt = 0; dt < 4; ++dt)
#pragma unroll
        for (int r = 0; r < 4; ++r)
            outb[(w * 16 + quad * 4 + r) * KQP + dt * 16 + l16] = f2bf(accO[dt][r]);
    __syncthreads();

    if (tid < 64) {
        const int n = qtick_hi[tid], s = qtick_lo[tid];
        logits[((size_t)bh * 2 + n) * 4096 + s] = lg[tid];
    }
    {
        const int qq = tid >> 2, part = tid & 3;
        const int n = qtick_hi[qq], s = qtick_lo[qq];
        const size_t ob = (((size_t)bh * 2 + n) * 4096 + s) * 64 + part * 16;
        u16x8 u0 = *(const u16x8*)&outb[qq * KQP + part * 16];
        u16x8 u1 = *(const u16x8*)&outb[qq * KQP + part * 16 + 8];
        *(u16x8*)(out_hash + ob)     = u0;
        *(u16x8*)(out_hash + ob + 8) = u1;
    }
}

// ---------------------------------------------------------------------------
// Kernel 5: combine hash rounds with logsumexp weights; emit fp32 [B,S,H*D].
// ---------------------------------------------------------------------------
__global__ __launch_bounds__(256)
void combine_kernel(const unsigned short* __restrict__ out_hash,
                    const float* __restrict__ logits,
                    float* __restrict__ out)
{
    const int idx  = blockIdx.x * 256 + threadIdx.x;   // < 2097152
    const int bh   = idx >> 16;
    const int rem  = idx & 65535;
    const int s    = rem >> 4;
    const int part = rem & 15;
    const float lg0 = logits[((size_t)bh * 2 + 0) * 4096 + s];
    const float lg1 = logits[((size_t)bh * 2 + 1) * 4096 + s];
    const float m  = fmaxf(lg0, lg1);
    const float e0 = expf(lg0 - m), e1 = expf(lg1 - m);
    const float inv = 1.0f / (e0 + e1);
    const float w0 = e0 * inv, w1 = e1 * inv;
    const size_t b0 = (((size_t)bh * 2 + 0) * 4096 + s) * 64 + part * 4;
    const size_t b1 = (((size_t)bh * 2 + 1) * 4096 + s) * 64 + part * 4;
    u16x4 u0 = *(const u16x4*)(out_hash + b0);
    u16x4 u1 = *(const u16x4*)(out_hash + b1);
    const int b = bh >> 4, hh = bh & 15;
    const size_t ob = ((size_t)b * 4096 + s) * 1024 + hh * 64 + part * 4;
    f32x4 r;
#pragma unroll
    for (int e = 0; e < 4; ++e)
        r[e] = w0 * bf2f(u0[e]) + w1 * bf2f(u1[e]);
    *(f32x4*)(out + ob) = r;
}

// ---------------------------------------------------------------------------
extern "C" void kernel_launch(void* const* d_in, const int* in_sizes, int n_in,
                              void* d_out, int out_size, void* d_ws, size_t ws_size,
                              hipStream_t stream) {
    const float* hidden = (const float*)d_in[0];   // [2,4096,1024] fp32
    const float* wqk    = (const float*)d_in[1];   // [1024,1024]   fp32
    const float* wv     = (const float*)d_in[2];   // [1024,1024]   fp32
    const float* rotf   = (const float*)d_in[3];   // [64,2,64]     fp32
    float* out = (float*)d_out;                    // [2,4096,1024] fp32

    char* ws = (char*)d_ws;
    float*          qk       = (float*)(ws);                       // 33,554,432 B
    unsigned short* vb       = (unsigned short*)(ws + 33554432);   // 16,777,216 B
    int*            buckets  = (int*)(ws + 50331648);              //  1,048,576 B
    int*            sorted   = (int*)(ws + 51380224);              //  1,048,576 B
    float*          logits   = (float*)(ws + 52428800);            //  1,048,576 B
    unsigned short* out_hash = (unsigned short*)(ws + 53477376);   // 33,554,432 B
    // total 87,031,808 B

    hipLaunchKernelGGL(gemm_qk,     dim3(64, 16),     dim3(256), 0, stream,
                       hidden, wqk, qk);
    hipLaunchKernelGGL(gemm_v,      dim3(64, 16),     dim3(256), 0, stream,
                       hidden, wv, vb);
    hipLaunchKernelGGL(hash_kernel, dim3(2048),       dim3(256), 0, stream,
                       qk, rotf, buckets);
    hipLaunchKernelGGL(sort_kernel, dim3(32),         dim3(256), 0, stream,
                       buckets, sorted);
    hipLaunchKernelGGL(attn_kernel, dim3(128, 16, 2), dim3(256), 0, stream,
                       qk, vb, sorted, out_hash, logits);
    hipLaunchKernelGGL(combine_kernel, dim3(8192),    dim3(256), 0, stream,
                       out_hash, logits, out);
}